// Round 1
// baseline (138.067 us; speedup 1.0000x reference)
//
#include <hip/hip_runtime.h>
#include <math.h>

namespace {

constexpr int B_TOTAL = 131072;
constexpr int T_STEPS = 32;

// Exact double-precision constant derivation (matches Python), rounded to f32 once.
constexpr double dG   = 9.81;
constexpr double dM   = 0.1667;
constexpr double dCAF = 5.0 * 0.25 * dM * dG;
constexpr double dCAR = dCAF;
constexpr double dLF  = 0.09 - 0.036;
constexpr double dLR  = 0.036;
constexpr double dIZ  = 0.000267;

constexpr float A33N = (float)(-(2.0 * dCAF + 2.0 * dCAR));                     // / (M*Vx)
constexpr float A35N = (float)(-(2.0 * dCAF * dLF - 2.0 * dCAR * dLR));         // / (M*Vx)
constexpr float A53N = (float)(-(2.0 * dLF * dCAF - 2.0 * dLR * dCAR));         // / (IZ*Vx)
constexpr float A55N = (float)(-(2.0 * dLF * dLF * dCAF + 2.0 * dLR * dLR * dCAR)); // / (IZ*Vx)
constexpr float ST1  = (float)(2.0 * dCAF / dM);          // * steer -> d3
constexpr float ST5  = (float)(2.0 * dLF * dCAF / dIZ);   // * steer -> d5
constexpr float MF   = (float)dM;
constexpr float IZF  = (float)dIZ;
constexpr float R0M  = (float)(0.05 * dG / dM);           // RES_BOUNDS[0]/M
constexpr float R1M  = (float)(0.05 * dG / dM);           // RES_BOUNDS[1]/M
constexpr float R2I  = (float)(0.05 * dG * 0.2 / dIZ);    // RES_BOUNDS[2]/IZ
constexpr float THR_OFF = 0.24f;
constexpr float THR_RAT = 6.98f;
constexpr float DT    = 0.01f;
constexpr float PI_F  = (float)3.14159265358979323846;
constexpr float TWOPI = (float)(2.0 * 3.14159265358979323846);
constexpr float INV2PI = (float)(1.0 / (2.0 * 3.14159265358979323846));

__device__ __forceinline__ float fast_tanh(float x) {
    // tanh(x) = (e^{2x}-1)/(e^{2x}+1); clamp so exp can't overflow.
    x = fminf(10.0f, fmaxf(-10.0f, x));
    const float e = __expf(x + x);
    return (e - 1.0f) * __builtin_amdgcn_rcpf(e + 1.0f);
}

__global__ __launch_bounds__(256)
void rollout_kernel(const float* __restrict__ fs,     // B x 4 x 8
                    const float* __restrict__ acts,   // B x 32 x 2
                    const float* __restrict__ w1g,    // 16 x 32
                    const float* __restrict__ b1g,    // 16
                    const float* __restrict__ w2g,    // 3 x 16
                    const float* __restrict__ b2g,    // 3
                    const int*   __restrict__ en,     // 1
                    float*       __restrict__ out)    // B x 32 x 8
{
    const int b = blockIdx.x * blockDim.x + threadIdx.x;
    if (b >= B_TOTAL) return;

    // window in registers (static indexing only -> VGPRs, rule #20)
    float w[32];
    {
        const float4* p = reinterpret_cast<const float4*>(fs + (size_t)b * 32);
        #pragma unroll
        for (int i = 0; i < 8; ++i) {
            const float4 v = p[i];
            w[4*i+0] = v.x; w[4*i+1] = v.y; w[4*i+2] = v.z; w[4*i+3] = v.w;
        }
    }

    const int rnn = *en;

    // biases: small, hoist once (uniform -> SGPRs)
    float bias1[16];
    #pragma unroll
    for (int j = 0; j < 16; ++j) bias1[j] = b1g[j];
    const float bias2_0 = b2g[0], bias2_1 = b2g[1], bias2_2 = b2g[2];

    const float2* ap = reinterpret_cast<const float2*>(acts) + (size_t)b * T_STEPS;
    float* op = out + (size_t)b * (T_STEPS * 8);

    // opaque, uniform offsets: redefined each iteration so the 560 weight
    // loads cannot be hoisted out of the t-loop (would spill), while the
    // address stays uniform (SGPR) so the backend can use scalar loads.
    int o1 = 0, o2 = 0;

    #pragma unroll 1
    for (int t = 0; t < T_STEPS; ++t) {
        asm volatile("" : "+s"(o1), "+s"(o2));
        const float* __restrict__ W1 = w1g + o1;
        const float* __restrict__ W2 = w2g + o2;

        const float s0 = w[24], s1 = w[25], s2 = w[26], s3 = w[27];
        const float s4 = w[28], s5 = w[29];
        const float thr = w[30], steer = w[31];

        float sn, c;
        __sincosf(s4, &sn, &c);

        const float Vx = s1 * c + s3 * sn;       // == v1 == d0
        const float v3 = c * s3 - sn * s1;
        const float v5 = s5;

        const float inv_mvx  = __builtin_amdgcn_rcpf(MF * Vx);
        const float inv_izvx = __builtin_amdgcn_rcpf(IZF * Vx);
        const float a33 = A33N * inv_mvx;
        const float a35 = -Vx + A35N * inv_mvx;
        const float a53 = A53N * inv_izvx;
        const float a55 = A55N * inv_izvx;

        const float d0 = Vx;
        float       d1 = (thr - THR_OFF) * THR_RAT;
        const float d2 = v3;
        float       d3 = a33 * v3 + a35 * v5 + ST1 * steer;
        const float d4 = v5;
        float       d5 = a53 * v3 + a55 * v5 + ST5 * steer;

        if (rnn) {
            float y1[16];
            #pragma unroll
            for (int j = 0; j < 16; ++j) {
                float acc = bias1[j];
                #pragma unroll
                for (int i = 0; i < 32; ++i)
                    acc = fmaf(w[i], W1[j * 32 + i], acc);
                y1[j] = fast_tanh(acc);
            }
            float z0 = bias2_0, z1 = bias2_1, z2 = bias2_2;
            #pragma unroll
            for (int j = 0; j < 16; ++j) {
                z0 = fmaf(y1[j], W2[0 * 16 + j], z0);
                z1 = fmaf(y1[j], W2[1 * 16 + j], z1);
                z2 = fmaf(y1[j], W2[2 * 16 + j], z2);
            }
            d1 += fast_tanh(z0) * R0M;
            d3 += fast_tanh(z1) * R1M;
            d5 += fast_tanh(z2) * R2I;
        }

        const float ns0 = s0 + (c * d0 - sn * d2) * DT;
        const float ns1 = s1 + (c * d1 - sn * d3) * DT;
        const float ns2 = s2 + (sn * d0 + c * d2) * DT;
        const float ns3 = s3 + (sn * d1 + c * d3) * DT;
        float aa = s4 + d4 * DT + PI_F;
        aa = aa - floorf(aa * INV2PI) * TWOPI;    // jnp.mod(aa, 2*pi)
        const float ns4 = aa - PI_F;
        const float ns5 = s5 + d5 * DT;

        const float2 act = ap[t];

        reinterpret_cast<float4*>(op)[2 * t + 0] = make_float4(ns0, ns1, ns2, ns3);
        reinterpret_cast<float4*>(op)[2 * t + 1] = make_float4(ns4, ns5, act.x, act.y);

        // shift window
        #pragma unroll
        for (int i = 0; i < 24; ++i) w[i] = w[i + 8];
        w[24] = ns0; w[25] = ns1; w[26] = ns2; w[27] = ns3;
        w[28] = ns4; w[29] = ns5; w[30] = act.x; w[31] = act.y;
    }
}

} // namespace

extern "C" void kernel_launch(void* const* d_in, const int* in_sizes, int n_in,
                              void* d_out, int out_size, void* d_ws, size_t ws_size,
                              hipStream_t stream) {
    const float* fs = (const float*)d_in[0];
    const float* ac = (const float*)d_in[1];
    const float* w1 = (const float*)d_in[2];
    const float* b1 = (const float*)d_in[3];
    const float* w2 = (const float*)d_in[4];
    const float* b2 = (const float*)d_in[5];
    const int*   en = (const int*)d_in[6];
    float* out = (float*)d_out;

    dim3 grid(B_TOTAL / 256), block(256);
    hipLaunchKernelGGL(rollout_kernel, grid, block, 0, stream,
                       fs, ac, w1, b1, w2, b2, en, out);
}

// Round 2
// 127.086 us; speedup vs baseline: 1.0864x; 1.0864x over previous
//
#include <hip/hip_runtime.h>
#include <math.h>

namespace {

constexpr int B_TOTAL = 131072;
constexpr int T_STEPS = 32;

// Exact double-precision constant derivation (matches Python), rounded to f32 once.
constexpr double dG   = 9.81;
constexpr double dM   = 0.1667;
constexpr double dCAF = 5.0 * 0.25 * dM * dG;
constexpr double dCAR = dCAF;
constexpr double dLF  = 0.09 - 0.036;
constexpr double dLR  = 0.036;
constexpr double dIZ  = 0.000267;

constexpr float A33N = (float)(-(2.0 * dCAF + 2.0 * dCAR));
constexpr float A35N = (float)(-(2.0 * dCAF * dLF - 2.0 * dCAR * dLR));
constexpr float A53N = (float)(-(2.0 * dLF * dCAF - 2.0 * dLR * dCAR));
constexpr float A55N = (float)(-(2.0 * dLF * dLF * dCAF + 2.0 * dLR * dLR * dCAR));
constexpr float ST1  = (float)(2.0 * dCAF / dM);
constexpr float ST5  = (float)(2.0 * dLF * dCAF / dIZ);
constexpr float MF   = (float)dM;
constexpr float IZF  = (float)dIZ;
constexpr float R0M  = (float)(0.05 * dG / dM);
constexpr float R1M  = (float)(0.05 * dG / dM);
constexpr float R2I  = (float)(0.05 * dG * 0.2 / dIZ);
constexpr float THR_OFF = 0.24f;
constexpr float THR_RAT = 6.98f;
constexpr float DT    = 0.01f;
constexpr float PI_F  = (float)3.14159265358979323846;
constexpr float TWOPI = (float)(2.0 * 3.14159265358979323846);
constexpr float INV2PI = (float)(1.0 / (2.0 * 3.14159265358979323846));

__device__ __forceinline__ float fast_tanh(float x) {
    x = fminf(10.0f, fmaxf(-10.0f, x));
    const float e = __expf(x + x);
    return (e - 1.0f) * __builtin_amdgcn_rcpf(e + 1.0f);
}

// LDS swizzle: float-element e (0..31) within row r -> spread b128 accesses
// across banks. XOR only touches bits >=2, so float2/float4 groups stay
// contiguous and aligned.
__device__ __forceinline__ int swz(int row, int e) { return e ^ ((row & 7) << 2); }

__global__ __launch_bounds__(256, 2)
void rollout_kernel(const float* __restrict__ fs,     // B x 4 x 8
                    const float* __restrict__ acts,   // B x 32 x 2
                    const float* __restrict__ w1g,    // 16 x 32
                    const float* __restrict__ b1g,    // 16
                    const float* __restrict__ w2g,    // 3 x 16
                    const float* __restrict__ b2g,    // 3
                    const int*   __restrict__ en,     // 1
                    float*       __restrict__ out)    // B x 32 x 8
{
    __shared__ float sbuf[256 * 32];   // init-state in / output staging (32 KB)
    __shared__ float abuf[256 * 32];   // action staging, 16 steps (32 KB)

    const int tid = threadIdx.x;
    const size_t blk_base = (size_t)blockIdx.x * 256;

    // ---- Phase 1: coalesced load of the block's 256x32 init-state region ----
    {
        const float4* fsb = reinterpret_cast<const float4*>(fs + blk_base * 32);
        #pragma unroll
        for (int k = 0; k < 8; ++k) {
            const int q   = k * 256 + tid;        // float4 idx in block region
            const int row = q >> 3;
            const int e   = (q & 7) << 2;
            const float4 v = fsb[q];
            *reinterpret_cast<float4*>(&sbuf[row * 32 + swz(row, e)]) = v;
        }
    }
    __syncthreads();

    float w[32];
    #pragma unroll
    for (int i = 0; i < 8; ++i) {
        const float4 v = *reinterpret_cast<const float4*>(&sbuf[tid * 32 + swz(tid, 4 * i)]);
        w[4*i+0] = v.x; w[4*i+1] = v.y; w[4*i+2] = v.z; w[4*i+3] = v.w;
    }

    const int rnn = *en;

    float bias1[16];
    #pragma unroll
    for (int j = 0; j < 16; ++j) bias1[j] = b1g[j];
    const float bias2_0 = b2g[0], bias2_1 = b2g[1], bias2_2 = b2g[2];

    // opaque uniform offsets: keep weight loads inside the t-loop (no giant
    // hoist -> no spills) while staying SGPR-addressed (scalar loads).
    int o1 = 0, o2 = 0;

    for (int tc = 0; tc < T_STEPS; tc += 4) {
        if ((tc & 15) == 0) {
            // ---- coalesced action staging: 16 steps = 128 B/thread = 1 line ----
            __syncthreads();
            #pragma unroll
            for (int k = 0; k < 8; ++k) {
                const int q   = k * 256 + tid;
                const int row = q >> 3;
                const int e   = (q & 7) << 2;
                const float4 v = *reinterpret_cast<const float4*>(
                    &acts[(blk_base + row) * 64 + tc * 2 + e]);
                *reinterpret_cast<float4*>(&abuf[row * 32 + swz(row, e)]) = v;
            }
            __syncthreads();
        }

        #pragma unroll 1
        for (int tl = 0; tl < 4; ++tl) {
            const int t = tc + tl;
            asm volatile("" : "+s"(o1), "+s"(o2));
            const float* __restrict__ W1 = w1g + o1;
            const float* __restrict__ W2 = w2g + o2;

            const float s0 = w[24], s1 = w[25], s2 = w[26], s3 = w[27];
            const float s4 = w[28], s5 = w[29];
            const float thr = w[30], steer = w[31];

            float sn, c;
            __sincosf(s4, &sn, &c);

            const float Vx = s1 * c + s3 * sn;
            const float v3 = c * s3 - sn * s1;
            const float v5 = s5;

            const float inv_mvx  = __builtin_amdgcn_rcpf(MF * Vx);
            const float inv_izvx = __builtin_amdgcn_rcpf(IZF * Vx);
            const float a33 = A33N * inv_mvx;
            const float a35 = -Vx + A35N * inv_mvx;
            const float a53 = A53N * inv_izvx;
            const float a55 = A55N * inv_izvx;

            const float d0 = Vx;
            float       d1 = (thr - THR_OFF) * THR_RAT;
            const float d2 = v3;
            float       d3 = a33 * v3 + a35 * v5 + ST1 * steer;
            const float d4 = v5;
            float       d5 = a53 * v3 + a55 * v5 + ST5 * steer;

            if (rnn) {
                float y1[16];
                #pragma unroll
                for (int j = 0; j < 16; ++j) {
                    float acc = bias1[j];
                    #pragma unroll
                    for (int i = 0; i < 32; ++i)
                        acc = fmaf(w[i], W1[j * 32 + i], acc);
                    y1[j] = fast_tanh(acc);
                }
                float z0 = bias2_0, z1 = bias2_1, z2 = bias2_2;
                #pragma unroll
                for (int j = 0; j < 16; ++j) {
                    z0 = fmaf(y1[j], W2[0 * 16 + j], z0);
                    z1 = fmaf(y1[j], W2[1 * 16 + j], z1);
                    z2 = fmaf(y1[j], W2[2 * 16 + j], z2);
                }
                d1 += fast_tanh(z0) * R0M;
                d3 += fast_tanh(z1) * R1M;
                d5 += fast_tanh(z2) * R2I;
            }

            const float ns0 = s0 + (c * d0 - sn * d2) * DT;
            const float ns1 = s1 + (c * d1 - sn * d3) * DT;
            const float ns2 = s2 + (sn * d0 + c * d2) * DT;
            const float ns3 = s3 + (sn * d1 + c * d3) * DT;
            float aa = s4 + d4 * DT + PI_F;
            aa = aa - floorf(aa * INV2PI) * TWOPI;
            const float ns4 = aa - PI_F;
            const float ns5 = s5 + d5 * DT;

            // action for this step from LDS (row = own tid)
            const float2 act = *reinterpret_cast<const float2*>(
                &abuf[tid * 32 + swz(tid, 2 * (t & 15))]);

            // stage outputs into sbuf (own row, swizzled)
            *reinterpret_cast<float4*>(&sbuf[tid * 32 + swz(tid, tl * 8)]) =
                make_float4(ns0, ns1, ns2, ns3);
            *reinterpret_cast<float4*>(&sbuf[tid * 32 + swz(tid, tl * 8 + 4)]) =
                make_float4(ns4, ns5, act.x, act.y);

            #pragma unroll
            for (int i = 0; i < 24; ++i) w[i] = w[i + 8];
            w[24] = ns0; w[25] = ns1; w[26] = ns2; w[27] = ns3;
            w[28] = ns4; w[29] = ns5; w[30] = act.x; w[31] = act.y;
        }

        // ---- flush 4-step output chunk, full 128-B lines per 8-lane group ----
        __syncthreads();
        #pragma unroll
        for (int k = 0; k < 8; ++k) {
            const int q   = k * 256 + tid;
            const int row = q >> 3;
            const int e   = (q & 7) << 2;
            const float4 v = *reinterpret_cast<const float4*>(&sbuf[row * 32 + swz(row, e)]);
            *reinterpret_cast<float4*>(&out[(blk_base + row) * 256 + tc * 8 + e]) = v;
        }
        __syncthreads();
    }
}

} // namespace

extern "C" void kernel_launch(void* const* d_in, const int* in_sizes, int n_in,
                              void* d_out, int out_size, void* d_ws, size_t ws_size,
                              hipStream_t stream) {
    const float* fs = (const float*)d_in[0];
    const float* ac = (const float*)d_in[1];
    const float* w1 = (const float*)d_in[2];
    const float* b1 = (const float*)d_in[3];
    const float* w2 = (const float*)d_in[4];
    const float* b2 = (const float*)d_in[5];
    const int*   en = (const int*)d_in[6];
    float* out = (float*)d_out;

    dim3 grid(B_TOTAL / 256), block(256);
    hipLaunchKernelGGL(rollout_kernel, grid, block, 0, stream,
                       fs, ac, w1, b1, w2, b2, en, out);
}

// Round 5
// 102.752 us; speedup vs baseline: 1.3437x; 1.2368x over previous
//
#include <hip/hip_runtime.h>
#include <math.h>

namespace {

typedef float f32x2 __attribute__((ext_vector_type(2)));

constexpr int B_TOTAL = 131072;
constexpr int T_STEPS = 32;

constexpr double dG   = 9.81;
constexpr double dM   = 0.1667;
constexpr double dCAF = 5.0 * 0.25 * dM * dG;
constexpr double dCAR = dCAF;
constexpr double dLF  = 0.09 - 0.036;
constexpr double dLR  = 0.036;
constexpr double dIZ  = 0.000267;

constexpr float A33N = (float)(-(2.0 * dCAF + 2.0 * dCAR));
constexpr float A35N = (float)(-(2.0 * dCAF * dLF - 2.0 * dCAR * dLR));
constexpr float A53N = (float)(-(2.0 * dLF * dCAF - 2.0 * dLR * dCAR));
constexpr float A55N = (float)(-(2.0 * dLF * dLF * dCAF + 2.0 * dLR * dLR * dCAR));
constexpr float ST1  = (float)(2.0 * dCAF / dM);
constexpr float ST5  = (float)(2.0 * dLF * dCAF / dIZ);
constexpr float MF   = (float)dM;
constexpr float IZF  = (float)dIZ;
constexpr float R0M  = (float)(0.05 * dG / dM);
constexpr float R1M  = (float)(0.05 * dG / dM);
constexpr float R2I  = (float)(0.05 * dG * 0.2 / dIZ);
constexpr float THR_OFF = 0.24f;
constexpr float THR_RAT = 6.98f;
constexpr float DT    = 0.01f;
constexpr float PI_F  = (float)3.14159265358979323846;
constexpr float TWOPI = (float)(2.0 * 3.14159265358979323846);
constexpr float INV2PI = (float)(1.0 / (2.0 * 3.14159265358979323846));
constexpr float TWO_LOG2E = 2.8853900817779268f;   // 2*log2(e)

__device__ __forceinline__ float fast_tanh(float x) {
    x = fminf(10.0f, fmaxf(-10.0f, x));
    const float e = __builtin_amdgcn_exp2f(x * TWO_LOG2E);
    return (e - 1.0f) * __builtin_amdgcn_rcpf(e + 1.0f);
}

// packed f32: 2 FMAs per issue slot, exact f32 FMA semantics.
// weight operand is wave-uniform -> SGPR pair (1 constant-bus read).
__device__ __forceinline__ void pk_fma(f32x2& acc, f32x2 x, f32x2 w) {
    asm("v_pk_fma_f32 %0, %1, %2, %0" : "+v"(acc) : "v"(x), "s"(w));
}
__device__ __forceinline__ f32x2 pk_mul(f32x2 x, f32x2 w) {
    f32x2 r;
    asm("v_pk_mul_f32 %0, %1, %2" : "=v"(r) : "v"(x), "s"(w));
    return r;
}

// LDS swizzle: float-element e (0..31) within row r.
__device__ __forceinline__ int swz(int row, int e) { return e ^ ((row & 7) << 2); }

__global__ __launch_bounds__(256, 2)
void rollout_kernel(const float* __restrict__ fs,     // B x 4 x 8
                    const float* __restrict__ acts,   // B x 32 x 2
                    const float* __restrict__ w1g,    // 16 x 32
                    const float* __restrict__ b1g,    // 16
                    const float* __restrict__ w2g,    // 3 x 16
                    const float* __restrict__ b2g,    // 3
                    const int*   __restrict__ en,     // 1
                    float*       __restrict__ out)    // B x 32 x 8
{
    __shared__ float sbuf[256 * 32];   // init-state in / output staging (32 KB)
    __shared__ float abuf[256 * 32];   // action staging, 16 steps (32 KB)

    const int tid = threadIdx.x;
    const size_t blk_base = (size_t)blockIdx.x * 256;

    // ---- coalesced load of the block's 256x32 init-state region ----
    {
        const float4* fsb = reinterpret_cast<const float4*>(fs + blk_base * 32);
        #pragma unroll
        for (int k = 0; k < 8; ++k) {
            const int q   = k * 256 + tid;
            const int row = q >> 3;
            const int e   = (q & 7) << 2;
            const float4 v = fsb[q];
            *reinterpret_cast<float4*>(&sbuf[row * 32 + swz(row, e)]) = v;
        }
    }
    __syncthreads();

    // 4-timestep window as 16 f32 pairs: group g (timestep slot) holds pairs
    // wp[g*4..g*4+3]. Statically rotated: at step t, oldest group = t&3.
    f32x2 wp[16];
    float s0, s1, s2, s3, s4, s5, thr, steer;
    {
        float w[32];
        #pragma unroll
        for (int i = 0; i < 8; ++i) {
            const float4 v = *reinterpret_cast<const float4*>(&sbuf[tid * 32 + swz(tid, 4 * i)]);
            w[4*i+0] = v.x; w[4*i+1] = v.y; w[4*i+2] = v.z; w[4*i+3] = v.w;
        }
        #pragma unroll
        for (int i = 0; i < 16; ++i) { wp[i].x = w[2*i]; wp[i].y = w[2*i+1]; }
        s0 = w[24]; s1 = w[25]; s2 = w[26]; s3 = w[27];
        s4 = w[28]; s5 = w[29]; thr = w[30]; steer = w[31];
    }

    const int rnn = *en;

    float bias1[16];
    #pragma unroll
    for (int j = 0; j < 16; ++j) bias1[j] = b1g[j];
    const float bias2_0 = b2g[0], bias2_1 = b2g[1], bias2_2 = b2g[2];

    const f32x2* w1p = reinterpret_cast<const f32x2*>(w1g);  // 16 rows x 16 pairs
    const f32x2* w2p = reinterpret_cast<const f32x2*>(w2g);  // 3 rows x 8 pairs

    // opaque uniform offset: keeps the per-step weight loads inside the loop
    // (no 280-pair hoist -> no spill) while staying SGPR-addressed.
    int o1 = 0;

    for (int tc = 0; tc < T_STEPS; tc += 4) {
        if ((tc & 15) == 0) {
            // ---- coalesced action staging: 16 steps = 128 B/thread ----
            __syncthreads();
            #pragma unroll
            for (int k = 0; k < 8; ++k) {
                const int q   = k * 256 + tid;
                const int row = q >> 3;
                const int e   = (q & 7) << 2;
                const float4 v = *reinterpret_cast<const float4*>(
                    &acts[(blk_base + row) * 64 + tc * 2 + e]);
                *reinterpret_cast<float4*>(&abuf[row * 32 + swz(row, e)]) = v;
            }
            __syncthreads();
        }

        #pragma unroll
        for (int tl = 0; tl < 4; ++tl) {           // fully unrolled; phase p = tl
            const int t = tc + tl;
            asm volatile("" : "+s"(o1));

            float sn, c;
            __sincosf(s4, &sn, &c);

            const float Vx = s1 * c + s3 * sn;
            const float v3 = c * s3 - sn * s1;
            const float v5 = s5;

            const float inv_mvx  = __builtin_amdgcn_rcpf(MF * Vx);
            const float inv_izvx = __builtin_amdgcn_rcpf(IZF * Vx);
            const float a33 = A33N * inv_mvx;
            const float a35 = -Vx + A35N * inv_mvx;
            const float a53 = A53N * inv_izvx;
            const float a55 = A55N * inv_izvx;

            const float d0 = Vx;
            float       d1 = (thr - THR_OFF) * THR_RAT;
            const float d2 = v3;
            float       d3 = a33 * v3 + a35 * v5 + ST1 * steer;
            const float d4 = v5;
            float       d5 = a53 * v3 + a55 * v5 + ST5 * steer;

            if (rnn) {
                // ordered pair i (0..15): timestep slot o=i>>2, within-slot k=i&3
                // physical index ((tl + o)&3)*4 + k   -- all compile-time.
                float y1[16];
                #pragma unroll
                for (int j = 0; j < 16; ++j) {
                    const f32x2* __restrict__ wrow = w1p + o1 + j * 16;
                    f32x2 acc = pk_mul(wp[((tl & 3) << 2)], wrow[0]);
                    #pragma unroll
                    for (int i = 1; i < 16; ++i) {
                        const int phys = (((tl + (i >> 2)) & 3) << 2) | (i & 3);
                        pk_fma(acc, wp[phys], wrow[i]);
                    }
                    y1[j] = fast_tanh(acc.x + acc.y + bias1[j]);
                }
                f32x2 y1p[8];
                #pragma unroll
                for (int i = 0; i < 8; ++i) { y1p[i].x = y1[2*i]; y1p[i].y = y1[2*i+1]; }

                f32x2 a0 = pk_mul(y1p[0], w2p[o1 + 0]);
                f32x2 a1 = pk_mul(y1p[0], w2p[o1 + 8]);
                f32x2 a2 = pk_mul(y1p[0], w2p[o1 + 16]);
                #pragma unroll
                for (int i = 1; i < 8; ++i) {
                    pk_fma(a0, y1p[i], w2p[o1 + i]);
                    pk_fma(a1, y1p[i], w2p[o1 + 8 + i]);
                    pk_fma(a2, y1p[i], w2p[o1 + 16 + i]);
                }
                d1 += fast_tanh(a0.x + a0.y + bias2_0) * R0M;
                d3 += fast_tanh(a1.x + a1.y + bias2_1) * R1M;
                d5 += fast_tanh(a2.x + a2.y + bias2_2) * R2I;
            }

            const float ns0 = s0 + (c * d0 - sn * d2) * DT;
            const float ns1 = s1 + (c * d1 - sn * d3) * DT;
            const float ns2 = s2 + (sn * d0 + c * d2) * DT;
            const float ns3 = s3 + (sn * d1 + c * d3) * DT;
            float aa = s4 + d4 * DT + PI_F;
            aa = aa - floorf(aa * INV2PI) * TWOPI;
            const float ns4 = aa - PI_F;
            const float ns5 = s5 + d5 * DT;

            const float2 act = *reinterpret_cast<const float2*>(
                &abuf[tid * 32 + swz(tid, 2 * (t & 15))]);

            // stage outputs into sbuf (own row, swizzled)
            *reinterpret_cast<float4*>(&sbuf[tid * 32 + swz(tid, tl * 8)]) =
                make_float4(ns0, ns1, ns2, ns3);
            *reinterpret_cast<float4*>(&sbuf[tid * 32 + swz(tid, tl * 8 + 4)]) =
                make_float4(ns4, ns5, act.x, act.y);

            // overwrite oldest window slot (group tl&3) with the new timestep
            {
                const int g = (tl & 3) << 2;
                wp[g+0].x = ns0;  wp[g+0].y = ns1;
                wp[g+1].x = ns2;  wp[g+1].y = ns3;
                wp[g+2].x = ns4;  wp[g+2].y = ns5;
                wp[g+3].x = act.x; wp[g+3].y = act.y;
            }

            s0 = ns0; s1 = ns1; s2 = ns2; s3 = ns3;
            s4 = ns4; s5 = ns5; thr = act.x; steer = act.y;
        }

        // ---- flush 4-step output chunk, full 128-B lines per 8-lane group ----
        __syncthreads();
        #pragma unroll
        for (int k = 0; k < 8; ++k) {
            const int q   = k * 256 + tid;
            const int row = q >> 3;
            const int e   = (q & 7) << 2;
            const float4 v = *reinterpret_cast<const float4*>(&sbuf[row * 32 + swz(row, e)]);
            *reinterpret_cast<float4*>(&out[(blk_base + row) * 256 + tc * 8 + e]) = v;
        }
        __syncthreads();
    }
}

} // namespace

extern "C" void kernel_launch(void* const* d_in, const int* in_sizes, int n_in,
                              void* d_out, int out_size, void* d_ws, size_t ws_size,
                              hipStream_t stream) {
    const float* fs = (const float*)d_in[0];
    const float* ac = (const float*)d_in[1];
    const float* w1 = (const float*)d_in[2];
    const float* b1 = (const float*)d_in[3];
    const float* w2 = (const float*)d_in[4];
    const float* b2 = (const float*)d_in[5];
    const int*   en = (const int*)d_in[6];
    float* out = (float*)d_out;

    dim3 grid(B_TOTAL / 256), block(256);
    hipLaunchKernelGGL(rollout_kernel, grid, block, 0, stream,
                       fs, ac, w1, b1, w2, b2, en, out);
}